// Round 10
// baseline (200.245 us; speedup 1.0000x reference)
//
#include <hip/hip_runtime.h>
#include <stdint.h>
#include <stddef.h>

typedef __attribute__((ext_vector_type(8))) short s16x8;
typedef __attribute__((ext_vector_type(4))) short s16x4;
typedef __attribute__((ext_vector_type(4))) float f32x4;
typedef __attribute__((ext_vector_type(16))) float f32x16;

#define B_  2
#define T_  2048
#define E_  1024
#define H_  16
#define E3_ 3072

// fp32 -> bf16, round-to-nearest-even
__device__ __forceinline__ short f2bf(float f) {
  union { float f; uint32_t u; } v; v.f = f;
  uint32_t u = v.u;
  return (short)((u + 0x7FFFu + ((u >> 16) & 1u)) >> 16);
}

__device__ __forceinline__ uint32_t fbits(float f) {
  union { float f; uint32_t u; } v; v.f = f; return v.u;
}

// async global->LDS, 16B per lane; lds dest = wave-uniform base + lane*16
__device__ __forceinline__ void gload_lds16(const short* g, short* l) {
  __builtin_amdgcn_global_load_lds(
      (__attribute__((address_space(1))) void*)(const_cast<short*>(g)),
      (__attribute__((address_space(3))) void*)(l), 16, 0, 0);
}

// ---------------- merged cast kernel (x, w_qkv, w_proj in one launch) -------
__global__ void castk_all(const float* __restrict__ x, const float* __restrict__ wqkv,
                          const float* __restrict__ wproj, short* __restrict__ xb,
                          short* __restrict__ wqkvb, short* __restrict__ wprojb) {
  const int bid = blockIdx.x;
  const float* in; short* out; int i; float sc = 1.0f;
  if (bid < 4096)      { in = x;     out = xb;     i = bid * 256 + threadIdx.x; }
  else if (bid < 7168) { in = wqkv;  out = wqkvb;  i = (bid - 4096) * 256 + threadIdx.x;
                         if (i < 262144) sc = 0.18033688011112042f; }
  else                 { in = wproj; out = wprojb; i = (bid - 7168) * 256 + threadIdx.x; }
  const float4 v = ((const float4*)in)[i];
  s16x4 o;
  o[0] = f2bf(v.x * sc); o[1] = f2bf(v.y * sc);
  o[2] = f2bf(v.z * sc); o[3] = f2bf(v.w * sc);
  ((s16x4*)out)[i] = o;
}

// ---------------- NT GEMM: C[M,N] = A[M,K] * B[N,K]^T (bf16 in, fp32 acc) ---
template <int MODE>
__global__ void gemm_nt_128(const short* __restrict__ A, const short* __restrict__ B,
                            void* __restrict__ Cv, short* __restrict__ vt,
                            int M, int N, int K) {
  __shared__ short As[128 * 32];
  __shared__ short Bs[128 * 32];
  const int tid  = threadIdx.x;
  const int lane = tid & 63;
  const int w    = tid >> 6;
  const int quad = lane >> 4;
  const int l16  = lane & 15;
  const int wm   = (w >> 1) * 64;
  const int wn   = (w & 1) * 64;
  const int bm   = blockIdx.y * 128;
  const int bn   = blockIdx.x * 128;

  f32x4 acc[4][4];
#pragma unroll
  for (int i = 0; i < 4; i++)
#pragma unroll
    for (int j = 0; j < 4; j++) acc[i][j] = (f32x4){0.f, 0.f, 0.f, 0.f};

  const int srow = w * 32 + (lane >> 2);
  const int scol = (lane & 3) * 8;
  const short* gA = A + (size_t)(bm + srow) * K + scol;
  const short* gB = B + (size_t)(bn + srow) * K + scol;
  short* lA = As + (w * 32) * 32;
  short* lB = Bs + (w * 32) * 32;

  for (int k0 = 0; k0 < K; k0 += 32) {
    __syncthreads();
    gload_lds16(gA + k0,          lA);
    gload_lds16(gA + 16 * K + k0, lA + 16 * 32);
    gload_lds16(gB + k0,          lB);
    gload_lds16(gB + 16 * K + k0, lB + 16 * 32);
    __syncthreads();

    s16x8 a[4], b[4];
#pragma unroll
    for (int i = 0; i < 4; i++)
      a[i] = *(const s16x8*)&As[(wm + i * 16 + l16) * 32 + quad * 8];
#pragma unroll
    for (int j = 0; j < 4; j++)
      b[j] = *(const s16x8*)&Bs[(wn + j * 16 + l16) * 32 + quad * 8];
#pragma unroll
    for (int i = 0; i < 4; i++)
#pragma unroll
      for (int j = 0; j < 4; j++)
        acc[i][j] = __builtin_amdgcn_mfma_f32_16x16x32_bf16(a[i], b[j], acc[i][j], 0, 0, 0);
  }

  if (MODE == 2 && bn >= 2 * E_) {
#pragma unroll
    for (int i = 0; i < 4; i++) {
      const int token = bm + wm + i * 16 + quad * 4;
      const int bb = token >> 11, t = token & (T_ - 1);
#pragma unroll
      for (int j = 0; j < 4; j++) {
        const int col = bn + wn + j * 16 + l16 - 2 * E_;  // h*64 + d
        s16x4 pk;
#pragma unroll
        for (int r = 0; r < 4; r++) pk[r] = f2bf(acc[i][j][r]);
        *(s16x4*)&vt[((size_t)(bb * H_ + (col >> 6)) * 64 + (col & 63)) * T_ + t] = pk;
      }
    }
  } else {
#pragma unroll
    for (int i = 0; i < 4; i++) {
      const int row0 = bm + wm + i * 16 + quad * 4;
#pragma unroll
      for (int j = 0; j < 4; j++) {
        const int col = bn + wn + j * 16 + l16;
#pragma unroll
        for (int r = 0; r < 4; r++) {
          const size_t idx = (size_t)(row0 + r) * N + col;
          if (MODE == 2) ((short*)Cv)[idx] = f2bf(acc[i][j][r]);
          else           ((float*)Cv)[idx] = acc[i][j][r];
        }
      }
    }
  }
}

// ---------------- flash attention: producer/consumer, 32x32 MFMA ------------
// 2 QK-waves produce P into a dbuf; 2 PV-waves consume P one kv-tile behind,
// reading V fragments DIRECTLY FROM GLOBAL (L2) -- V never enters LDS. LDS =
// K dbuf + P dbuf = 32768 B -> 4 blocks/CU with 1024-block LPT grid. Row sums
// via ones-MFMA. R8/R9 bug (fixed): staging global addresses omitted the
// per-lane row term srl*E3_ (gload_lds16 lands lane L at LDS row L>>3, so
// the global source must add srl = lane>>3 rows) -> every K octet held 8
// copies of its first row.
__global__ void __launch_bounds__(256, 4)
attn_kernel(const short* __restrict__ qkv, const short* __restrict__ vt,
            short* __restrict__ attout) {
  __shared__ short Ks[2][64 * 64];  // [kv][d], 16B-granule row-XOR swizzled
  __shared__ short Ps[2][64 * 64];  // [q][kv], 16B-granule row-XOR swizzled
  const int tid  = threadIdx.x;
  const int lane = tid & 63;
  const int w    = tid >> 6;
  const int l32  = lane & 31;
  const int hi   = lane >> 5;          // 0,1
  const int bh = blockIdx.x;
  const int b = bh >> 4, h = bh & 15;
  const int qt = 31 - (int)blockIdx.y; // LPT: heavy first
  const int q0b = qt * 64;
  const int nkv = qt + 1;              // kv tiles 0..nkv-1
  // role assignment XOR'd with block parity so QK/PV mix across SIMDs
  const int rid = w ^ (int)(blockIdx.y & 1);
  const int pv  = rid & 1;             // 0 = QK producer, 1 = PV consumer
  const int qh  = rid >> 1;            // q half (32 rows)
  const int qw  = q0b + qh * 32;
  const float NEG_INF = -__builtin_inff();
  const int key = l32 & 7;

  // K staging: wave stages rows [16w, 16w+16); lane L covers row (L>>3) of
  // its octet, granule position L&7 holding global granule (L&7)^(row&7).
  const int srl = lane >> 3;
  const int sgc = ((lane & 7) ^ srl) * 8;
  const short* gK = qkv + (size_t)(b * T_) * E3_ + E_ + h * 64 + sgc;

  s16x8 ones;
#pragma unroll
  for (int i = 0; i < 8; i++) ones[i] = (short)0x3F80;  // bf16 1.0

  // --- per-role loop-invariant state ---
  s16x8 qf[4];                 // QK: Q B-frags (pre-scaled by log2e/8)
  int koff[2][4];              // QK: Ks fragment offsets
  int pwoff[2][4];             // QK: P write offsets (b64 quads)
  int poff[4];                 // PV: P read offsets (b128)
  const short* gv0 = nullptr;  // PV: V global base

  if (!pv) {
    const short* qb = qkv + (size_t)(b * T_ + qw + l32) * E3_ + h * 64 + hi * 8;
#pragma unroll
    for (int c = 0; c < 4; c++) qf[c] = *(const s16x8*)(qb + c * 16);
#pragma unroll
    for (int kvh = 0; kvh < 2; kvh++) {
#pragma unroll
      for (int c = 0; c < 4; c++)
        koff[kvh][c] = 2 * ((kvh * 32 + l32) * 64 + (((c * 2 + hi) ^ key) * 8));
#pragma unroll
      for (int qg = 0; qg < 4; qg++)
        pwoff[kvh][qg] = 2 * ((qh * 32 + l32) * 64) + (((kvh * 4 + qg) ^ key) * 16) + hi * 8;
    }
  } else {
#pragma unroll
    for (int c = 0; c < 4; c++)
      poff[c] = 2 * ((qh * 32 + l32) * 64) + (((c * 2 + hi) ^ key) * 16);
    gv0 = vt + (size_t)(bh * 64 + l32) * T_ + hi * 8;
  }

  f32x16 o0, o1, ol;
#pragma unroll
  for (int i = 0; i < 16; i++) { o0[i] = 0.f; o1[i] = 0.f; ol[i] = 0.f; }

  // prologue: stage K tile 0 into buffer 0 (rows w*16+srl, w*16+8+srl)
  gload_lds16(gK + (size_t)(w * 16 + srl) * E3_,     &Ks[0][(w * 16) * 64]);
  gload_lds16(gK + (size_t)(w * 16 + 8 + srl) * E3_, &Ks[0][(w * 16 + 8) * 64]);
  __syncthreads();

  for (int g = 0; g <= nkv; g++) {
    // stage K tile g+1 (exists if g+1 <= nkv-1)
    if (g + 1 < nkv) {
      const short* gKs = gK + (size_t)((g + 1) * 64 + w * 16 + srl) * E3_;
      gload_lds16(gKs,           &Ks[(g + 1) & 1][(w * 16) * 64]);
      gload_lds16(gKs + 8 * E3_, &Ks[(g + 1) & 1][(w * 16 + 8) * 64]);
    }

    if (!pv) {
      if (g < nkv) {  // QK on tile g
        const char* kb = (const char*)&Ks[g & 1][0];
        char* pb = (char*)&Ps[g & 1][0];
        f32x16 sc0, sc1;
#pragma unroll
        for (int i = 0; i < 16; i++) { sc0[i] = 0.f; sc1[i] = 0.f; }
#pragma unroll
        for (int c = 0; c < 4; c++) {
          const s16x8 kf0 = *(const s16x8*)(kb + koff[0][c]);
          const s16x8 kf1 = *(const s16x8*)(kb + koff[1][c]);
          sc0 = __builtin_amdgcn_mfma_f32_32x32x16_bf16(kf0, qf[c], sc0, 0, 0, 0);
          sc1 = __builtin_amdgcn_mfma_f32_32x32x16_bf16(kf1, qf[c], sc1, 0, 0, 0);
        }
        if (g == nkv - 1) {  // diagonal tile: mask kv > q
#pragma unroll
          for (int r = 0; r < 16; r++) {
            const int kvl = (r & 3) + 8 * (r >> 2) + 4 * hi;
            const int ql = qh * 32 + l32;
            if (kvl > ql)      sc0[r] = NEG_INF;
            if (kvl + 32 > ql) sc1[r] = NEG_INF;
          }
        }
        // exp2 + pack reg-quads (kv-consecutive) -> b64
#pragma unroll
        for (int kvh = 0; kvh < 2; kvh++) {
#pragma unroll
          for (int qg = 0; qg < 4; qg++) {
            const float p0 = exp2f(kvh ? sc1[qg * 4 + 0] : sc0[qg * 4 + 0]);
            const float p1 = exp2f(kvh ? sc1[qg * 4 + 1] : sc0[qg * 4 + 1]);
            const float p2 = exp2f(kvh ? sc1[qg * 4 + 2] : sc0[qg * 4 + 2]);
            const float p3 = exp2f(kvh ? sc1[qg * 4 + 3] : sc0[qg * 4 + 3]);
            int2 pk;
            pk.x = (int)__builtin_amdgcn_perm(fbits(p1), fbits(p0), 0x07060302u);
            pk.y = (int)__builtin_amdgcn_perm(fbits(p3), fbits(p2), 0x07060302u);
            *(int2*)(pb + pwoff[kvh][qg]) = pk;
          }
        }
      }
    } else {
      if (g > 0) {  // PV on tile g-1, P from Ps[(g-1)&1], V from global
        const char* pbr = (const char*)&Ps[(g - 1) & 1][0];
        const short* gvt = gv0 + (g - 1) * 64;
        s16x8 pf[4];
#pragma unroll
        for (int c = 0; c < 4; c++) pf[c] = *(const s16x8*)(pbr + poff[c]);
#pragma unroll
        for (int c = 0; c < 4; c++) {
          const s16x8 vf0 = *(const s16x8*)(gvt + c * 16);
          const s16x8 vf1 = *(const s16x8*)(gvt + (size_t)32 * T_ + c * 16);
          ol = __builtin_amdgcn_mfma_f32_32x32x16_bf16(pf[c], ones, ol, 0, 0, 0);
          o0 = __builtin_amdgcn_mfma_f32_32x32x16_bf16(pf[c], vf0, o0, 0, 0, 0);
          o1 = __builtin_amdgcn_mfma_f32_32x32x16_bf16(pf[c], vf1, o1, 0, 0, 0);
        }
      }
    }

    __syncthreads();  // P(g) published; K tile g+1 landed; WAR fences
  }

  // epilogue: PV waves normalize and write [b,t,h,d] bf16
  if (pv) {
#pragma unroll
    for (int r = 0; r < 16; r++) {
      const float inv = 1.0f / ol[r];
      const int q = qw + (r & 3) + 8 * (r >> 2) + 4 * hi;
      short* ob = attout + ((size_t)(b * T_ + q) * H_ + h) * 64 + l32;
      ob[0]  = f2bf(o0[r] * inv);
      ob[32] = f2bf(o1[r] * inv);
    }
  }
}

// ---------------- launch -----------------------------------------------------
extern "C" void kernel_launch(void* const* d_in, const int* in_sizes, int n_in,
                              void* d_out, int out_size, void* d_ws, size_t ws_size,
                              hipStream_t stream) {
  const float* x     = (const float*)d_in[0];   // [4096, 1024] fp32
  const float* wqkv  = (const float*)d_in[1];   // [3072, 1024] fp32
  const float* wproj = (const float*)d_in[2];   // [1024, 1024] fp32

  if (ws_size < 58720256u) return;
  short* ws     = (short*)d_ws;
  short* xb     = ws;                    // 4096*1024
  short* wqkvb  = xb + 4194304;          // 3072*1024
  short* wprojb = wqkvb + 3145728;       // 1024*1024
  short* qkv    = wprojb + 1048576;      // 4096*3072 (V third unused)
  short* vt     = qkv + 12582912;        // 2*16*64*2048
  short* attb   = vt + 4194304;          // 4096*1024

  castk_all<<<8192, 256, 0, stream>>>(x, wqkv, wproj, xb, wqkvb, wprojb);
  gemm_nt_128<2><<<dim3(24, 32), 256, 0, stream>>>(xb, wqkvb, qkv, vt, 4096, 3072, 1024);
  attn_kernel<<<dim3(32, 32), 256, 0, stream>>>(qkv, vt, attb);
  gemm_nt_128<0><<<dim3(8, 32), 256, 0, stream>>>(attb, wprojb, d_out, nullptr, 4096, 1024, 1024);
}